// Round 5
// baseline (320.654 us; speedup 1.0000x reference)
//
#include <hip/hip_runtime.h>

// GRU decoder via MFMA, round 9: B=32768, T=48, F=16, H=32.
// OCCUPANCY RESTRUCTURE (4-wave split). Round-8 counters: VALUBusy 54%,
// MfmaUtil 10%, HBM 10%, Occupancy 36% -> latency/issue-bound with occupancy
// grid-capped at 16 waves/CU (2048 blocks x 2 waves). This round: block =
// 256 thr = 4 waves per 16-batch-row tile -> 8192 waves = 32/CU = 8/SIMD.
// Wave (half=w&1, khalf=w>>1): khalf0 computes W*x (3 MFMAs, feat K=16),
// khalf1 computes R*h (3 MFMAs, full K=32) for hidden cols [16*half,+16).
// Partial gate planes (xz,xr,xh | hz,hr,hh) exchanged via LDS f32 planes
// (XOR-swizzled b128 writes, b64 reads); activations redistributed over all
// 256 threads (2 elements/thread, halving per-lane transcendental chain).
// Two raw lgkm-only barriers per step (imm 0xC07F -- no vmcnt drain),
// single-buffered LDS (2-barrier schedule makes dbuf unnecessary).
// po (dense out) kept in f32 via per-element fmaf AFTER the exchange --
// numerically identical to round 7's fmaf(po,wz4,acc) path.
// Activation uses 5-trans form: shared rcp for sigmoid(z)+tanh combine:
// h = ((Dv-2)*Ez + hc*Dv) * rcp(Dv*(1+Ez)), Ez=exp2(Sz), Dv=1+exp2(vv).
// Safe here: |logits| << 127 with this data distribution (weights ~0.1).
// Layouts (verified m89/m91/m120):
//   D[m=gatecol][n=batchcol]: col=lane&15=batch, row=(lane>>4)*4+reg=gatecol
//   A[m=lane&15][k=(lane>>4)*8+j] ; B[k=(lane>>4)*8+j][n=lane&15]

typedef __attribute__((ext_vector_type(8))) short short8;
typedef __attribute__((ext_vector_type(4))) float f32x4;
typedef __attribute__((ext_vector_type(2))) float f32x2;

constexpr int T_STEPS   = 48;
constexpr int F_DIM     = 16;
constexpr int H_DIM     = 32;
constexpr int O_STRIDE  = 17;     // obuf leading stride (floats)
constexpr int HP_STRIDE = 20;     // hplane row stride (u32) - pad vs 16 banks
constexpr int PLANE_DW  = 512;    // one gate plane: 16 batch x 32 hidden f32

union S8 { short8 s; unsigned u[4]; };

__device__ __forceinline__ unsigned pk_bf16(float hi, float lo) {
    // (bf16(hi)<<16)|bf16(lo), round-half-up
    return __builtin_amdgcn_perm(__float_as_uint(hi) + 0x8000u,
                                 __float_as_uint(lo) + 0x8000u, 0x07060302u);
}
__device__ __forceinline__ short bf16s(float x) {
    return (short)((__float_as_uint(x) + 0x8000u) >> 16);
}
__device__ __forceinline__ float rcpf(float x) { return __builtin_amdgcn_rcpf(x); }
__device__ __forceinline__ float ex2(float x)  { return __builtin_amdgcn_exp2f(x); }
#define MFMA(a, b, c) __builtin_amdgcn_mfma_f32_16x16x32_bf16(a, b, c, 0, 0, 0)
#define SWZ(v, off) __int_as_float(__builtin_amdgcn_ds_swizzle(__float_as_int(v), (off)))

__global__ __launch_bounds__(256, 8)
void gru_mfma9(const float* __restrict__ feat,     // [B,T,F]
               const float* __restrict__ init_in,  // [B,1]
               const float* __restrict__ init_h,   // [B,H]
               const float* __restrict__ Wk,       // [17,96]
               const float* __restrict__ Rk,       // [32,96]
               const float* __restrict__ bx,       // [96]
               const float* __restrict__ bh,       // [96]
               const float* __restrict__ dw,       // [32]
               const float* __restrict__ db,       // [1]
               float* __restrict__ out)            // [B,T]
{
    __shared__ __align__(16) float    gp[6 * PLANE_DW];        // 12 KB gate planes
    __shared__ __align__(16) unsigned hpl[16 * HP_STRIDE];     // h tile (bf16x2)
    __shared__ float posum[16];                                // prev dense out
    __shared__ __align__(16) float    obuf[T_STEPS * O_STRIDE];

    const int tid  = threadIdx.x;          // 0..255
    const int lane = tid & 63;
    const int wv   = tid >> 6;             // wave 0..3
    const int half = wv & 1;               // hidden col group
    const int kh   = wv >> 1;              // 0: W*x, 1: R*h
    const int ln   = lane & 15;            // batch col (MFMA)
    const int quad = lane >> 4;
    const int b0   = blockIdx.x * 16;
    const int ab   = tid >> 4;             // activation batch row 0..15
    const int ah   = (tid & 15) * 2;       // activation hidden pair base

    const float SZ = -1.44269504088896340736f;   // -log2(e)  (sigmoid args)
    const float SC =  2.88539008177792681472f;   // 2*log2(e) (tanh arg)

    // ---- A-operand weight fragments (this wave's hidden half) ----
    S8 Az, Ar, Ah;
#pragma unroll
    for (int j = 0; j < 8; ++j) {
        const int k = quad * 8 + j;
        const int n = half * 16 + ln;
        if (kh) {
            Az.s[j] = bf16s(SZ * Rk[(size_t)k * 96 + n]);
            Ar.s[j] = bf16s(SZ * Rk[(size_t)k * 96 + 32 + n]);
            Ah.s[j] = bf16s(SC * Rk[(size_t)k * 96 + 64 + n]);
        } else {
            const float wz = (k < 16) ? Wk[(size_t)(k + 1) * 96 + n]      : 0.0f;
            const float wr = (k < 16) ? Wk[(size_t)(k + 1) * 96 + 32 + n] : 0.0f;
            const float wh = (k < 16) ? Wk[(size_t)(k + 1) * 96 + 64 + n] : 0.0f;
            Az.s[j] = bf16s(SZ * wz); Ar.s[j] = bf16s(SZ * wr); Ah.s[j] = bf16s(SC * wh);
        }
    }

    // ---- MFMA accumulator bias init (biases ride on khalf0; hh bias on khalf1) ----
    f32x4 cz, cr, ch;
#pragma unroll
    for (int i = 0; i < 4; ++i) {
        const int c = half * 16 + quad * 4 + i;
        cz[i] = kh ? 0.0f : SZ * (bx[c] + bh[c]);
        cr[i] = kh ? 0.0f : SZ * (bx[32 + c] + bh[32 + c]);
        ch[i] = SC * (kh ? bh[64 + c] : bx[64 + c]);
    }

    // ---- per-thread activation constants & state (2 hidden units) ----
    float hc0 = init_h[(size_t)(b0 + ab) * H_DIM + ah];
    float hc1 = init_h[(size_t)(b0 + ab) * H_DIM + ah + 1];
    const float dw0 = dw[ah], dw1 = dw[ah + 1];
    const float wzp0 = SZ * Wk[ah],      wzp1 = SZ * Wk[ah + 1];       // prev_out row
    const float wrp0 = SZ * Wk[32 + ah], wrp1 = SZ * Wk[32 + ah + 1];
    const float whp0 = SC * Wk[64 + ah], whp1 = SC * Wk[64 + ah + 1];
    const float dbs = db[0];

    // init h plane + posum (previous output = init_in)
    hpl[ab * HP_STRIDE + (ah >> 1)] = pk_bf16(hc1, hc0);
    if ((tid & 15) == 0) posum[ab] = init_in[b0 + ab];

    // ---- feat prefetch (khalf0 waves only) ----
    const float* fqb = feat + (size_t)(b0 + ln) * (T_STEPS * F_DIM) + (quad & 1) * 8;
    f32x4 pa, pb;
    if (!kh) { pa = *(const f32x4*)fqb; pb = *(const f32x4*)(fqb + 4); }

    // ---- LDS addresses ----
    // gate plane write: XOR batch bits into col bits -> 2-way max on b128
    const int gw  = kh * 3 * PLANE_DW + ln * 32
                  + ((half * 16 + quad * 4) ^ ((ln & 7) << 2));
    const int grd = ab * 32 + (ah ^ ((ab & 7) << 2));      // + plane*512
    const int hrd = ln * HP_STRIDE + quad * 4;             // B-frag read (u32)
    const int hwr = ab * HP_STRIDE + (ah >> 1);            // h write (u32)

    __syncthreads();
    S8 bop;                                     // B-operand: x (kh0) or h (kh1)
    if (kh) bop.s = *(const short8*)&hpl[hrd];

    for (int t = 0; t < T_STEPS; ++t) {
        // ===== MFMA phase =====
        if (!kh) {
            if (quad < 2) {
                bop.u[0] = pk_bf16(pa[1], pa[0]); bop.u[1] = pk_bf16(pa[3], pa[2]);
                bop.u[2] = pk_bf16(pb[1], pb[0]); bop.u[3] = pk_bf16(pb[3], pb[2]);
            } else {
                bop.u[0] = 0; bop.u[1] = 0; bop.u[2] = 0; bop.u[3] = 0;
            }
            const int t1 = (t < T_STEPS - 1) ? t + 1 : t;  // prefetch next
            pa = *(const f32x4*)(fqb + t1 * F_DIM);
            pb = *(const f32x4*)(fqb + t1 * F_DIM + 4);
        }
        f32x4 aZ = cz, aR = cr, aH = ch;
        aZ = MFMA(Az.s, bop.s, aZ);
        aR = MFMA(Ar.s, bop.s, aR);
        aH = MFMA(Ah.s, bop.s, aH);
        *(f32x4*)&gp[gw]                = aZ;
        *(f32x4*)&gp[gw + PLANE_DW]     = aR;
        *(f32x4*)&gp[gw + 2 * PLANE_DW] = aH;
        __builtin_amdgcn_s_waitcnt(0xC07F);    // lgkmcnt(0) only
        __builtin_amdgcn_s_barrier();          // B1: planes ready

        // ===== activation phase (2 elements per thread) =====
        const float po1 = posum[ab];           // prev step's dense out (f32)
        const f32x2 xz = *(const f32x2*)&gp[grd];
        const f32x2 xr = *(const f32x2*)&gp[grd + PLANE_DW];
        const f32x2 xh = *(const f32x2*)&gp[grd + 2 * PLANE_DW];
        const f32x2 hz = *(const f32x2*)&gp[grd + 3 * PLANE_DW];
        const f32x2 hr = *(const f32x2*)&gp[grd + 4 * PLANE_DW];
        const f32x2 hh = *(const f32x2*)&gp[grd + 5 * PLANE_DW];

        float h0n, h1n;
        {   // e = 0
            const float Sr = fmaf(po1, wrp0, xr[0] + hr[0]);
            const float rr = rcpf(1.0f + ex2(Sr));
            const float vv = fmaf(rr, hh[0], fmaf(po1, whp0, xh[0]));
            const float Ez = ex2(fmaf(po1, wzp0, xz[0] + hz[0]));
            const float Dv = 1.0f + ex2(vv);
            const float num = fmaf(hc0, Dv, (Dv - 2.0f) * Ez);
            const float den = fmaf(Dv, Ez, Dv);
            h0n = num * rcpf(den);
        }
        {   // e = 1
            const float Sr = fmaf(po1, wrp1, xr[1] + hr[1]);
            const float rr = rcpf(1.0f + ex2(Sr));
            const float vv = fmaf(rr, hh[1], fmaf(po1, whp1, xh[1]));
            const float Ez = ex2(fmaf(po1, wzp1, xz[1] + hz[1]));
            const float Dv = 1.0f + ex2(vv);
            const float num = fmaf(hc1, Dv, (Dv - 2.0f) * Ez);
            const float den = fmaf(Dv, Ez, Dv);
            h1n = num * rcpf(den);
        }
        hc0 = h0n; hc1 = h1n;
        hpl[hwr] = pk_bf16(h1n, h0n);

        // dense: sum h*dw over 16 threads of this batch row (butterfly xor)
        float s = fmaf(h0n, dw0, h1n * dw1);
        s += SWZ(s, 0x041F);                   // xor 1
        s += SWZ(s, 0x081F);                   // xor 2
        s += SWZ(s, 0x101F);                   // xor 4
        s += SWZ(s, 0x201F);                   // xor 8
        const float po = s + dbs;
        if ((tid & 15) == 0) { posum[ab] = po; obuf[t * O_STRIDE + ab] = po; }
        __builtin_amdgcn_s_waitcnt(0xC07F);    // lgkmcnt(0) only
        __builtin_amdgcn_s_barrier();          // B2: h/posum ready
        if (kh) bop.s = *(const short8*)&hpl[hrd];
    }

    // ---- flush outputs (first wave): coalesced dwordx4 ----
    if (tid < 64) {
        const int row = tid >> 2;              // 0..15
        const int tb  = (tid & 3) * 12;        // 0,12,24,36
        float* orow = out + (size_t)(b0 + row) * T_STEPS + tb;
#pragma unroll
        for (int k = 0; k < 3; ++k) {
            f32x4 v;
#pragma unroll
            for (int e = 0; e < 4; ++e) v[e] = obuf[(tb + k * 4 + e) * O_STRIDE + row];
            *(f32x4*)(orow + k * 4) = v;
        }
    }
}

extern "C" void kernel_launch(void* const* d_in, const int* in_sizes, int n_in,
                              void* d_out, int out_size, void* d_ws, size_t ws_size,
                              hipStream_t stream) {
    const float* feat    = (const float*)d_in[0];
    const float* init_in = (const float*)d_in[1];
    const float* init_h  = (const float*)d_in[2];
    const float* Wk      = (const float*)d_in[3];
    const float* Rk      = (const float*)d_in[4];
    const float* bx      = (const float*)d_in[5];
    const float* bh      = (const float*)d_in[6];
    const float* dw      = (const float*)d_in[7];
    const float* db      = (const float*)d_in[8];
    float* out           = (float*)d_out;

    const int B = in_sizes[2] / H_DIM;      // 32768
    dim3 grid((unsigned)(B / 16));          // one 4-wave block per 16 batch rows
    dim3 block(256);
    hipLaunchKernelGGL(gru_mfma9, grid, block, 0, stream,
                       feat, init_in, init_h, Wk, Rk, bx, bh, dw, db, out);
}

// Round 6
// 184.709 us; speedup vs baseline: 1.7360x; 1.7360x over previous
//
#include <hip/hip_runtime.h>

// GRU decoder via MFMA, round 10: B=32768, T=48, F=16, H=32.
// R9 post-mortem: 4-wave split regressed 76->207us (VALUBusy 54->23%) --
// per-step sync chain, not wave supply, is the bottleneck. Back to R8's
// verified 2-wave pair-split skeleton with THREE deltas:
//  (1) DUAL-TILE ILP: block owns 32 batch rows = two 16-row tiles; each wave
//      runs both tiles' recurrences (12 MFMA + 8 gate elems per step) ->
//      two independent chains fill each other's stalls; ONE barrier per step
//      covers both tiles (barrier cost per work halved). Grid 1024 blocks.
//  (2) po IN MFMA K: prev_out enters as bf16 hi+lo pair in K slots 16/17
//      (Wk row 0 weights duplicated there) -> kills 12 dependent fmaf(po,.)
//      per lane-step; hi+lo keeps ~16 mantissa bits.
//  (3) 5-trans gates (R9-validated): h = (hc*Dv + Ez*(Dv-2))/(Dv*(1+Ez)),
//      Ez=exp2(z-arg), Dv=1+exp2(tanh-arg); 3 ex2 + 2 rcp per elem.
// Exchange of h_new (bf16 B-frag) + dense half-sums via parity-dbuf LDS with
// ONE raw s_barrier per step preceded by lgkm-only wait (0xC07F) -- vmcnt
// prefetch stays in flight (m97 lesson).
// Layouts (verified m89/m91/m120):
//   D[m=gatecol][n=batchcol]: col=lane&15=batch, row=(lane>>4)*4+reg=gatecol
//   A[m=lane&15][k=(lane>>4)*8+j] ; B[k=(lane>>4)*8+j][n=lane&15]

typedef __attribute__((ext_vector_type(8))) short short8;
typedef __attribute__((ext_vector_type(4))) float f32x4;

constexpr int T_STEPS  = 48;
constexpr int F_DIM    = 16;
constexpr int H_DIM    = 32;
constexpr int ROW_SH   = 40;              // shorts per h-row (80 B, 16B-aligned)
constexpr int HX_SH    = 16 * ROW_SH;     // one h buffer: 640 shorts
constexpr int O_STRIDE = 17;              // obuf leading stride (floats)

union S8 { short8 s; unsigned u[4]; };

__device__ __forceinline__ unsigned pk_bf16(float hi, float lo) {
    // (bf16(hi)<<16)|bf16(lo), round-half-up
    return __builtin_amdgcn_perm(__float_as_uint(hi) + 0x8000u,
                                 __float_as_uint(lo) + 0x8000u, 0x07060302u);
}
__device__ __forceinline__ short bf16s(float x) {
    return (short)((__float_as_uint(x) + 0x8000u) >> 16);
}
__device__ __forceinline__ float rcpf(float x) { return __builtin_amdgcn_rcpf(x); }
__device__ __forceinline__ float ex2(float x)  { return __builtin_amdgcn_exp2f(x); }
#define MFMA(a, b, c) __builtin_amdgcn_mfma_f32_16x16x32_bf16(a, b, c, 0, 0, 0)
#define SWZ16(v) __int_as_float(__builtin_amdgcn_ds_swizzle(__float_as_int(v), 0x401F))
#define BPERM(a, v) __builtin_amdgcn_ds_bpermute((a), (v))

__global__ __launch_bounds__(128, 2)
void gru_mfma10(const float* __restrict__ feat,     // [B,T,F]
                const float* __restrict__ init_in,  // [B,1]
                const float* __restrict__ init_h,   // [B,H]
                const float* __restrict__ Wk,       // [17,96]
                const float* __restrict__ Rk,       // [32,96]
                const float* __restrict__ bx,       // [96]
                const float* __restrict__ bh,       // [96]
                const float* __restrict__ dw,       // [32]
                const float* __restrict__ db,       // [1]
                float* __restrict__ out)            // [B,T]
{
    // hx layout: [tile(2)][parity(2)][HX_SH shorts]
    __shared__ __align__(16) short hx[4 * HX_SH];
    __shared__ float posumf[2 * 2 * 2 * 16];           // [tile][parity][wave][col]
    __shared__ __align__(16) float obuf[2 * T_STEPS * O_STRIDE];

    const int lane = threadIdx.x & 63;
    const int w    = threadIdx.x >> 6;        // 0/1: hidden half owned
    const int ln   = lane & 15;               // batch col
    const int quad = lane >> 4;
    const int b0   = blockIdx.x * 32;         // 32 rows: tile0 = +0, tile1 = +16
    const int bpa  = (lane ^ 32) << 2;        // xor32 bpermute addr

    const float SZ = -1.44269504088896340736f;   // -log2(e)  (sigmoid args)
    const float SC =  2.88539008177792681472f;   // 2*log2(e) (tanh arg)

    // ---- weight A-frags for this wave's hidden half; K rows 16/17 = Wk row 0
    S8 Wfz, Wfr, Wfh, Rfz, Rfr, Rfh;
#pragma unroll
    for (int j = 0; j < 8; ++j) {
        const int k = quad * 8 + j;
        const int n = w * 16 + ln;
        float wz = 0.0f, wr = 0.0f, wh = 0.0f;
        if (k < 16) {                    // feat rows
            wz = Wk[(size_t)(k + 1) * 96 + n];
            wr = Wk[(size_t)(k + 1) * 96 + 32 + n];
            wh = Wk[(size_t)(k + 1) * 96 + 64 + n];
        } else if (k < 18) {             // k=16: po_hi, k=17: po_lo (same row 0)
            wz = Wk[n];
            wr = Wk[32 + n];
            wh = Wk[64 + n];
        }
        Wfz.s[j] = bf16s(SZ * wz); Wfr.s[j] = bf16s(SZ * wr); Wfh.s[j] = bf16s(SC * wh);
        Rfz.s[j] = bf16s(SZ * Rk[(size_t)k * 96 + n]);
        Rfr.s[j] = bf16s(SZ * Rk[(size_t)k * 96 + 32 + n]);
        Rfh.s[j] = bf16s(SC * Rk[(size_t)k * 96 + 64 + n]);
    }

    // ---- per-lane gate constants (4 elements of this wave's half) ----
    float bz4[4], br4[4], bxh4[4], bhh4[4], dw4[4];
#pragma unroll
    for (int i = 0; i < 4; ++i) {
        const int c = w * 16 + quad * 4 + i;
        bz4[i]  = SZ * (bx[c] + bh[c]);
        br4[i]  = SZ * (bx[32 + c] + bh[32 + c]);
        bxh4[i] = SC * bx[64 + c];
        bhh4[i] = SC * bh[64 + c];
        dw4[i]  = dw[c];
    }
    const float dbs = db[0];

    // ---- initial state, both tiles ----
    float hc0[4], hc1[4];
#pragma unroll
    for (int i = 0; i < 4; ++i) {
        hc0[i] = init_h[(size_t)(b0 + ln) * H_DIM + w * 16 + quad * 4 + i];
        hc1[i] = init_h[(size_t)(b0 + 16 + ln) * H_DIM + w * 16 + quad * 4 + i];
    }
    S8 hB0, hB1;
    {
        const float* hp0 = init_h + (size_t)(b0 + ln) * H_DIM + quad * 8;
        const float* hp1 = init_h + (size_t)(b0 + 16 + ln) * H_DIM + quad * 8;
        f32x4 a = *(const f32x4*)hp0, b = *(const f32x4*)(hp0 + 4);
        hB0.u[0] = pk_bf16(a[1], a[0]); hB0.u[1] = pk_bf16(a[3], a[2]);
        hB0.u[2] = pk_bf16(b[1], b[0]); hB0.u[3] = pk_bf16(b[3], b[2]);
        a = *(const f32x4*)hp1; b = *(const f32x4*)(hp1 + 4);
        hB1.u[0] = pk_bf16(a[1], a[0]); hB1.u[1] = pk_bf16(a[3], a[2]);
        hB1.u[2] = pk_bf16(b[1], b[0]); hB1.u[3] = pk_bf16(b[3], b[2]);
    }
    float po0 = init_in[b0 + ln];
    float po1 = init_in[b0 + 16 + ln];

    // ---- feat prefetch, depth 2, both tiles ----
    const float* fq0 = feat + (size_t)(b0 + ln) * (T_STEPS * F_DIM) + (quad & 1) * 8;
    const float* fq1 = feat + (size_t)(b0 + 16 + ln) * (T_STEPS * F_DIM) + (quad & 1) * 8;
    f32x4 p0a0 = *(const f32x4*)(fq0);
    f32x4 p0b0 = *(const f32x4*)(fq0 + 4);
    f32x4 p0a1 = *(const f32x4*)(fq0 + F_DIM);
    f32x4 p0b1 = *(const f32x4*)(fq0 + F_DIM + 4);
    f32x4 p1a0 = *(const f32x4*)(fq1);
    f32x4 p1b0 = *(const f32x4*)(fq1 + 4);
    f32x4 p1a1 = *(const f32x4*)(fq1 + F_DIM);
    f32x4 p1b1 = *(const f32x4*)(fq1 + F_DIM + 4);

    // LDS addresses for the h exchange (tile/parity offsets added statically)
    unsigned* hwr = (unsigned*)(hx + ln * ROW_SH + w * 16 + quad * 4);  // write own half
    const short8* hrd = (const short8*)(hx + ln * ROW_SH + quad * 8);   // read full

    // One step, BOTH tiles, one barrier. T_ time, P_ parity (literal),
    // PA_/PB_ tile0 feat regs, QA_/QB_ tile1 feat regs (consumed, refilled t+2).
#define STEP2(T_, P_, PA_, PB_, QA_, QB_) do {                                 \
        S8 xa0, xa1;                                                           \
        {                                                                      \
            const unsigned zm = (quad < 2) ? 0xFFFFFFFFu : 0u;                 \
            xa0.u[0] = pk_bf16(PA_[1], PA_[0]) & zm;                           \
            xa0.u[1] = pk_bf16(PA_[3], PA_[2]) & zm;                           \
            xa0.u[2] = pk_bf16(PB_[1], PB_[0]) & zm;                           \
            xa0.u[3] = pk_bf16(PB_[3], PB_[2]) & zm;                           \
            xa1.u[0] = pk_bf16(QA_[1], QA_[0]) & zm;                           \
            xa1.u[1] = pk_bf16(QA_[3], QA_[2]) & zm;                           \
            xa1.u[2] = pk_bf16(QB_[1], QB_[0]) & zm;                           \
            xa1.u[3] = pk_bf16(QB_[3], QB_[2]) & zm;                           \
            if (quad == 2) {  /* po as bf16 hi+lo in K slots 16/17 */          \
                const float h0 = __uint_as_float(                              \
                    (__float_as_uint(po0) + 0x8000u) & 0xFFFF0000u);           \
                const float h1 = __uint_as_float(                              \
                    (__float_as_uint(po1) + 0x8000u) & 0xFFFF0000u);           \
                xa0.u[0] = pk_bf16(po0 - h0, h0);                              \
                xa1.u[0] = pk_bf16(po1 - h1, h1);                              \
            }                                                                  \
        }                                                                      \
        {   /* prefetch feat(T_+2), stays in flight across the barrier */      \
            const int t2 = ((T_) + 2 < T_STEPS) ? (T_) + 2 : T_STEPS - 1;      \
            PA_ = *(const f32x4*)(fq0 + t2 * F_DIM);                           \
            PB_ = *(const f32x4*)(fq0 + t2 * F_DIM + 4);                       \
            QA_ = *(const f32x4*)(fq1 + t2 * F_DIM);                           \
            QB_ = *(const f32x4*)(fq1 + t2 * F_DIM + 4);                       \
        }                                                                      \
        /* 12 MFMAs: 6 per tile (independent chains) */                        \
        f32x4 aZ0 = {bz4[0], bz4[1], bz4[2], bz4[3]};                          \
        f32x4 aR0 = {br4[0], br4[1], br4[2], br4[3]};                          \
        f32x4 aH0 = {bxh4[0], bxh4[1], bxh4[2], bxh4[3]};                      \
        f32x4 aG0 = {bhh4[0], bhh4[1], bhh4[2], bhh4[3]};                      \
        f32x4 aZ1 = aZ0, aR1 = aR0, aH1 = aH0, aG1 = aG0;                      \
        aZ0 = MFMA(Wfz.s, xa0.s, aZ0);  aZ1 = MFMA(Wfz.s, xa1.s, aZ1);         \
        aR0 = MFMA(Wfr.s, xa0.s, aR0);  aR1 = MFMA(Wfr.s, xa1.s, aR1);         \
        aH0 = MFMA(Wfh.s, xa0.s, aH0);  aH1 = MFMA(Wfh.s, xa1.s, aH1);         \
        aZ0 = MFMA(Rfz.s, hB0.s, aZ0);  aZ1 = MFMA(Rfz.s, hB1.s, aZ1);         \
        aR0 = MFMA(Rfr.s, hB0.s, aR0);  aR1 = MFMA(Rfr.s, hB1.s, aR1);         \
        aG0 = MFMA(Rfh.s, hB0.s, aG0);  aG1 = MFMA(Rfh.s, hB1.s, aG1);         \
        /* gates: 5-trans form (R9-validated numerics) */                      \
        float hn0[4], hn1[4];                                                  \
        _Pragma("unroll")                                                      \
        for (int i = 0; i < 4; ++i) {                                          \
            {                                                                  \
                const float Ez = ex2(aZ0[i]);                                  \
                const float rr = rcpf(1.0f + ex2(aR0[i]));                     \
                const float vv = fmaf(rr, aG0[i], aH0[i]);                     \
                const float Dv = 1.0f + ex2(vv);                               \
                const float num = fmaf(hc0[i], Dv, (Dv - 2.0f) * Ez);          \
                const float den = fmaf(Dv, Ez, Dv);                            \
                const float h2 = num * rcpf(den);                              \
                hc0[i] = h2; hn0[i] = h2;                                      \
            }                                                                  \
            {                                                                  \
                const float Ez = ex2(aZ1[i]);                                  \
                const float rr = rcpf(1.0f + ex2(aR1[i]));                     \
                const float vv = fmaf(rr, aG1[i], aH1[i]);                     \
                const float Dv = 1.0f + ex2(vv);                               \
                const float num = fmaf(hc1[i], Dv, (Dv - 2.0f) * Ez);          \
                const float den = fmaf(Dv, Ez, Dv);                            \
                const float h2 = num * rcpf(den);                              \
                hc1[i] = h2; hn1[i] = h2;                                      \
            }                                                                  \
        }                                                                      \
        /* dense half-sums (both tiles) */                                     \
        float s0 = fmaf(hn0[0], dw4[0], hn0[1] * dw4[1])                       \
                 + fmaf(hn0[2], dw4[2], hn0[3] * dw4[3]);                      \
        float s1 = fmaf(hn1[0], dw4[0], hn1[1] * dw4[1])                       \
                 + fmaf(hn1[2], dw4[2], hn1[3] * dw4[3]);                      \
        s0 += SWZ16(s0); s1 += SWZ16(s1);                                      \
        s0 += __int_as_float(BPERM(bpa, __float_as_int(s0)));                  \
        s1 += __int_as_float(BPERM(bpa, __float_as_int(s1)));                  \
        /* publish h_new halves + half-sums, both tiles */                     \
        {                                                                      \
            unsigned* hw0 = hwr + (0 * 2 + (P_)) * (HX_SH / 2);                \
            unsigned* hw1 = hwr + (2 + (P_)) * (HX_SH / 2);                    \
            hw0[0] = pk_bf16(hn0[1], hn0[0]);                                  \
            hw0[1] = pk_bf16(hn0[3], hn0[2]);                                  \
            hw1[0] = pk_bf16(hn1[1], hn1[0]);                                  \
            hw1[1] = pk_bf16(hn1[3], hn1[2]);                                  \
            if (lane < 16) {                                                   \
                posumf[((0 * 2 + (P_)) * 2 + w) * 16 + lane] = s0;             \
                posumf[((2 + (P_)) * 2 + w) * 16 + lane] = s1;                 \
            }                                                                  \
        }                                                                      \
        /* ONE raw barrier: lgkm only, vmem prefetch stays in flight */        \
        __builtin_amdgcn_s_waitcnt(0xC07F);                                    \
        __builtin_amdgcn_s_barrier();                                          \
        /* read full h B-frags + other half-sums */                            \
        hB0.s = hrd[(0 * 2 + (P_)) * (HX_SH / 8)];                             \
        hB1.s = hrd[(2 + (P_)) * (HX_SH / 8)];                                 \
        po0 = s0 + posumf[((0 * 2 + (P_)) * 2 + (1 - w)) * 16 + ln] + dbs;     \
        po1 = s1 + posumf[((2 + (P_)) * 2 + (1 - w)) * 16 + ln] + dbs;         \
        if (lane < 16) {                                                       \
            if (w == 0) obuf[(T_) * O_STRIDE + lane] = po0;                    \
            else        obuf[T_STEPS * O_STRIDE + (T_) * O_STRIDE + lane] = po1;\
        }                                                                      \
    } while (0)

    for (int t = 0; t < T_STEPS; t += 2) {
        STEP2(t,     0, p0a0, p0b0, p1a0, p1b0);
        STEP2(t + 1, 1, p0a1, p0b1, p1a1, p1b1);
    }
#undef STEP2

    // ---- flush outputs: wave w flushes tile w (coalesced dwordx4) ----
    __syncthreads();
    {
        const float* ob = obuf + w * (T_STEPS * O_STRIDE);
        const int row = lane >> 2;                 // 0..15
        const int tb  = (lane & 3) * 12;           // 0,12,24,36
        float* orow = out + (size_t)(b0 + w * 16 + row) * T_STEPS + tb;
#pragma unroll
        for (int k = 0; k < 3; ++k) {
            f32x4 v;
#pragma unroll
            for (int e = 0; e < 4; ++e) v[e] = ob[(tb + k * 4 + e) * O_STRIDE + row];
            *(f32x4*)(orow + k * 4) = v;
        }
    }
}

extern "C" void kernel_launch(void* const* d_in, const int* in_sizes, int n_in,
                              void* d_out, int out_size, void* d_ws, size_t ws_size,
                              hipStream_t stream) {
    const float* feat    = (const float*)d_in[0];
    const float* init_in = (const float*)d_in[1];
    const float* init_h  = (const float*)d_in[2];
    const float* Wk      = (const float*)d_in[3];
    const float* Rk      = (const float*)d_in[4];
    const float* bx      = (const float*)d_in[5];
    const float* bh      = (const float*)d_in[6];
    const float* dw      = (const float*)d_in[7];
    const float* db      = (const float*)d_in[8];
    float* out           = (float*)d_out;

    const int B = in_sizes[2] / H_DIM;      // 32768
    dim3 grid((unsigned)(B / 32));          // one 2-wave block per 32 batch rows
    dim3 block(128);
    hipLaunchKernelGGL(gru_mfma10, grid, block, 0, stream,
                       feat, init_in, init_h, Wk, Rk, bx, bh, dw, db, out);
}

// Round 9
// 173.144 us; speedup vs baseline: 1.8519x; 1.0668x over previous
//
#include <hip/hip_runtime.h>

// GRU decoder via MFMA, round 11: B=32768, T=48, F=16, H=32.
// BARRIER-FREE SINGLE-WAVE RECURRENCE. R8/R9/R10 established the bottleneck
// is the per-step cross-wave sync chain (ds_write h -> lgkm -> s_barrier ->
// ds_read hB ~120cy), which exists only because hidden cols were split
// across waves. Fix: PERMUTED GATE-COLUMN ORDER in the MFMA m-dim:
//   tile A cols = hidden [0-3, 8-11,16-19,24-27], tile B = [4-7,12-15,...]
//   i.e. hid(r,T) = (r>>2)*8 + T*4 + (r&3).
// With this ordering, D-output lane (quad,ln) holds hidden q*8+T*4+i for
// batch ln -- exactly the 8 values its NEXT-step B-frag needs (k=q*8+j).
// The h recurrence is fully lane-local: no LDS h-exchange, NO BARRIERS.
// One wave per 16 batch rows runs all 12 MFMAs/step (z,r,hh x A,B x W,R).
// Weights/biases/dw permuted identically -> numerics unchanged vs R10
// (absmax 0.0078125 verified there). Dense out: 8-elem dot + xor16 swizzle
// + xor32 bpermute (in-wave, no barrier). po enters MFMA K slots 16/17 as
// bf16 hi+lo (R10-verified). 5-trans gates (R9/R10-verified):
//   h = (hc*Dv + Ez*(Dv-2)) / (Dv*(1+Ez)), Ez=exp2(zarg), Dv=1+exp2(varg).
// Grid 2048 x 64thr = 8 blocks/CU co-resident, ~140 VGPR, LDS only obuf.
// Layouts (verified m89/m91/m120):
//   D[m][n]: col=lane&15=batch, row=(lane>>4)*4+reg  (m = PERMUTED gatecol)
//   A[m=lane&15][k=(lane>>4)*8+j] ; B[k=(lane>>4)*8+j][n=lane&15]

typedef __attribute__((ext_vector_type(8))) short short8;
typedef __attribute__((ext_vector_type(4))) float f32x4;

constexpr int T_STEPS  = 48;
constexpr int F_DIM    = 16;
constexpr int H_DIM    = 32;
constexpr int O_STRIDE = 17;              // obuf leading stride (floats)

union S8 { short8 s; unsigned u[4]; };

__device__ __forceinline__ unsigned pk_bf16(float hi, float lo) {
    // (bf16(hi)<<16)|bf16(lo), round-half-up
    return __builtin_amdgcn_perm(__float_as_uint(hi) + 0x8000u,
                                 __float_as_uint(lo) + 0x8000u, 0x07060302u);
}
__device__ __forceinline__ short bf16s(float x) {
    return (short)((__float_as_uint(x) + 0x8000u) >> 16);
}
__device__ __forceinline__ float rcpf(float x) { return __builtin_amdgcn_rcpf(x); }
__device__ __forceinline__ float ex2(float x)  { return __builtin_amdgcn_exp2f(x); }
#define MFMA(a, b, c) __builtin_amdgcn_mfma_f32_16x16x32_bf16(a, b, c, 0, 0, 0)
#define SWZ16(v) __int_as_float(__builtin_amdgcn_ds_swizzle(__float_as_int(v), 0x401F))
#define BPERM(a, v) __builtin_amdgcn_ds_bpermute((a), (v))

__global__ __launch_bounds__(64, 2)
void gru_mfma11(const float* __restrict__ feat,     // [B,T,F]
                const float* __restrict__ init_in,  // [B,1]
                const float* __restrict__ init_h,   // [B,H]
                const float* __restrict__ Wk,       // [17,96]
                const float* __restrict__ Rk,       // [32,96]
                const float* __restrict__ bx,       // [96]
                const float* __restrict__ bh,       // [96]
                const float* __restrict__ dw,       // [32]
                const float* __restrict__ db,       // [1]
                float* __restrict__ out)            // [B,T]
{
    __shared__ __align__(16) float obuf[T_STEPS * O_STRIDE];

    const int lane = threadIdx.x;             // block = 64 = ONE wave
    const int ln   = lane & 15;               // batch col
    const int quad = lane >> 4;
    const int b0   = blockIdx.x * 16;
    const int bpa  = (lane ^ 32) << 2;        // xor32 bpermute addr

    const float SZ = -1.44269504088896340736f;   // -log2(e)  (sigmoid args)
    const float SC =  2.88539008177792681472f;   // 2*log2(e) (tanh arg)

    // Permuted A-column for this lane's m-row (ln): cA(T) = (ln>>2)*8+T*4+(ln&3)
    const int cA0 = (ln >> 2) * 8 + (ln & 3);
    const int cA1 = cA0 + 4;

    // ---- A-operand weight fragments, 6 m-tiles x {W,R} ----
    S8 WzA, WrA, WhA, WzB, WrB, WhB, RzA, RrA, RhA, RzB, RrB, RhB;
#pragma unroll
    for (int j = 0; j < 8; ++j) {
        const int k = quad * 8 + j;
        float wzA = 0, wrA = 0, whA = 0, wzB = 0, wrB = 0, whB = 0;
        if (k < 16) {                       // feat rows 0..15 -> Wk rows 1..16
            const float* Wrow = Wk + (size_t)(k + 1) * 96;
            wzA = Wrow[cA0]; wrA = Wrow[32 + cA0]; whA = Wrow[64 + cA0];
            wzB = Wrow[cA1]; wrB = Wrow[32 + cA1]; whB = Wrow[64 + cA1];
        } else if (k < 18) {                // k=16: po_hi, k=17: po_lo (Wk row 0)
            wzA = Wk[cA0]; wrA = Wk[32 + cA0]; whA = Wk[64 + cA0];
            wzB = Wk[cA1]; wrB = Wk[32 + cA1]; whB = Wk[64 + cA1];
        }
        WzA.s[j] = bf16s(SZ * wzA); WrA.s[j] = bf16s(SZ * wrA); WhA.s[j] = bf16s(SC * whA);
        WzB.s[j] = bf16s(SZ * wzB); WrB.s[j] = bf16s(SZ * wrB); WhB.s[j] = bf16s(SC * whB);
        const float* Rrow = Rk + (size_t)k * 96;
        RzA.s[j] = bf16s(SZ * Rrow[cA0]); RrA.s[j] = bf16s(SZ * Rrow[32 + cA0]);
        RhA.s[j] = bf16s(SC * Rrow[64 + cA0]);
        RzB.s[j] = bf16s(SZ * Rrow[cA1]); RrB.s[j] = bf16s(SZ * Rrow[32 + cA1]);
        RhB.s[j] = bf16s(SC * Rrow[64 + cA1]);
    }

    // ---- per-lane D-side constants: c = quad*8 + T*4 + i ----
    f32x4 czA, crA, chA, cgA, czB, crB, chB, cgB, dwA, dwB;
#pragma unroll
    for (int i = 0; i < 4; ++i) {
        const int c0 = quad * 8 + i, c1 = c0 + 4;
        czA[i] = SZ * (bx[c0] + bh[c0]);           czB[i] = SZ * (bx[c1] + bh[c1]);
        crA[i] = SZ * (bx[32 + c0] + bh[32 + c0]); crB[i] = SZ * (bx[32 + c1] + bh[32 + c1]);
        chA[i] = SC * bx[64 + c0];                 chB[i] = SC * bx[64 + c1];
        cgA[i] = SC * bh[64 + c0];                 cgB[i] = SC * bh[64 + c1];
        dwA[i] = dw[c0];                           dwB[i] = dw[c1];
    }
    const float dbs = db[0];

    // ---- initial state (lane-local, permuted layout) ----
    f32x4 hcA, hcB;
#pragma unroll
    for (int i = 0; i < 4; ++i) {
        hcA[i] = init_h[(size_t)(b0 + ln) * H_DIM + quad * 8 + i];
        hcB[i] = init_h[(size_t)(b0 + ln) * H_DIM + quad * 8 + 4 + i];
    }
    S8 hB;                                     // B-frag: k=q*8+j natural order
    hB.u[0] = pk_bf16(hcA[1], hcA[0]);
    hB.u[1] = pk_bf16(hcA[3], hcA[2]);
    hB.u[2] = pk_bf16(hcB[1], hcB[0]);
    hB.u[3] = pk_bf16(hcB[3], hcB[2]);

    float po = init_in[b0 + ln];

    // ---- feat prefetch, depth 2 ----
    const float* fqb = feat + (size_t)(b0 + ln) * (T_STEPS * F_DIM) + (quad & 1) * 8;
    f32x4 pa0 = *(const f32x4*)(fqb);
    f32x4 pb0 = *(const f32x4*)(fqb + 4);
    f32x4 pa1 = *(const f32x4*)(fqb + F_DIM);
    f32x4 pb1 = *(const f32x4*)(fqb + F_DIM + 4);

    // One step: NO barrier, NO LDS in the recurrence (obuf write off-chain).
#define GRU_STEP(T_, PA_, PB_) do {                                            \
        S8 xa;                                                                 \
        {                                                                      \
            const unsigned zm = (quad < 2) ? 0xFFFFFFFFu : 0u;                 \
            xa.u[0] = pk_bf16(PA_[1], PA_[0]) & zm;                            \
            xa.u[1] = pk_bf16(PA_[3], PA_[2]) & zm;                            \
            xa.u[2] = pk_bf16(PB_[1], PB_[0]) & zm;                            \
            xa.u[3] = pk_bf16(PB_[3], PB_[2]) & zm;                            \
            if (quad == 2) {   /* po as bf16 hi+lo in K slots 16/17 */         \
                const float ph = __uint_as_float(                              \
                    (__float_as_uint(po) + 0x8000u) & 0xFFFF0000u);            \
                xa.u[0] = pk_bf16(po - ph, ph);                                \
            }                                                                  \
        }                                                                      \
        {   /* prefetch feat(T_+2) */                                          \
            const int t2 = ((T_) + 2 < T_STEPS) ? (T_) + 2 : T_STEPS - 1;      \
            PA_ = *(const f32x4*)(fqb + t2 * F_DIM);                           \
            PB_ = *(const f32x4*)(fqb + t2 * F_DIM + 4);                       \
        }                                                                      \
        /* 12 MFMAs: 6 m-tiles x {W,R} */                                      \
        f32x4 aZA = czA, aRA = crA, aHA = chA, aGA = cgA;                      \
        f32x4 aZB = czB, aRB = crB, aHB = chB, aGB = cgB;                      \
        aZA = MFMA(WzA.s, xa.s, aZA);  aZB = MFMA(WzB.s, xa.s, aZB);           \
        aRA = MFMA(WrA.s, xa.s, aRA);  aRB = MFMA(WrB.s, xa.s, aRB);           \
        aHA = MFMA(WhA.s, xa.s, aHA);  aHB = MFMA(WhB.s, xa.s, aHB);           \
        aZA = MFMA(RzA.s, hB.s, aZA);  aZB = MFMA(RzB.s, hB.s, aZB);           \
        aRA = MFMA(RrA.s, hB.s, aRA);  aRB = MFMA(RrB.s, hB.s, aRB);           \
        aGA = MFMA(RhA.s, hB.s, aGA);  aGB = MFMA(RhB.s, hB.s, aGB);           \
        /* gates: 5-trans form (R9/R10-validated) */                           \
        _Pragma("unroll")                                                      \
        for (int i = 0; i < 4; ++i) {                                          \
            {                                                                  \
                const float Ez = ex2(aZA[i]);                                  \
                const float rr = rcpf(1.0f + ex2(aRA[i]));                     \
                const float vv = fmaf(rr, aGA[i], aHA[i]);                     \
                const float Dv = 1.0f + ex2(vv);                               \
                const float num = fmaf(hcA[i], Dv, (Dv - 2.0f) * Ez);          \
                const float den = fmaf(Dv, Ez, Dv);                            \
                hcA[i] = num * rcpf(den);                                      \
            }                                                                  \
            {                                                                  \
                const float Ez = ex2(aZB[i]);                                  \
                const float rr = rcpf(1.0f + ex2(aRB[i]));                     \
                const float vv = fmaf(rr, aGB[i], aHB[i]);                     \
                const float Dv = 1.0f + ex2(vv);                               \
                const float num = fmaf(hcB[i], Dv, (Dv - 2.0f) * Ez);          \
                const float den = fmaf(Dv, Ez, Dv);                            \
                hcB[i] = num * rcpf(den);                                      \
            }                                                                  \
        }                                                                      \
        /* repack B-frag for next step (lane-local, no exchange!) */           \
        hB.u[0] = pk_bf16(hcA[1], hcA[0]);                                     \
        hB.u[1] = pk_bf16(hcA[3], hcA[2]);                                     \
        hB.u[2] = pk_bf16(hcB[1], hcB[0]);                                     \
        hB.u[3] = pk_bf16(hcB[3], hcB[2]);                                     \
        /* dense: own 8 units, then cross-quad xor16+xor32 reduce */           \
        float s = fmaf(hcA[0], dwA[0], hcA[1] * dwA[1]);                       \
        s = fmaf(hcA[2], dwA[2], s);                                           \
        s = fmaf(hcA[3], dwA[3], s);                                           \
        s = fmaf(hcB[0], dwB[0], s);                                           \
        s = fmaf(hcB[1], dwB[1], s);                                           \
        s = fmaf(hcB[2], dwB[2], s);                                           \
        s = fmaf(hcB[3], dwB[3], s);                                           \
        s += SWZ16(s);                                                         \
        s += __int_as_float(BPERM(bpa, __float_as_int(s)));                    \
        po = s + dbs;                                                          \
        if (lane < 16) obuf[(T_) * O_STRIDE + lane] = po;                      \
    } while (0)

    for (int t = 0; t < T_STEPS; t += 2) {
        GRU_STEP(t,     pa0, pb0);
        GRU_STEP(t + 1, pa1, pb1);
    }
#undef GRU_STEP

    // ---- flush outputs (single wave): coalesced dwordx4 ----
    __builtin_amdgcn_s_waitcnt(0xC07F);            // drain obuf ds_writes
    {
        const int row = lane >> 2;                 // 0..15
        const int tb  = (lane & 3) * 12;           // 0,12,24,36
        float* orow = out + (size_t)(b0 + row) * T_STEPS + tb;
#pragma unroll
        for (int k = 0; k < 3; ++k) {
            f32x4 v;
#pragma unroll
            for (int e = 0; e < 4; ++e) v[e] = obuf[(tb + k * 4 + e) * O_STRIDE + row];
            *(f32x4*)(orow + k * 4) = v;
        }
    }
}

extern "C" void kernel_launch(void* const* d_in, const int* in_sizes, int n_in,
                              void* d_out, int out_size, void* d_ws, size_t ws_size,
                              hipStream_t stream) {
    const float* feat    = (const float*)d_in[0];
    const float* init_in = (const float*)d_in[1];
    const float* init_h  = (const float*)d_in[2];
    const float* Wk      = (const float*)d_in[3];
    const float* Rk      = (const float*)d_in[4];
    const float* bx      = (const float*)d_in[5];
    const float* bh      = (const float*)d_in[6];
    const float* dw      = (const float*)d_in[7];
    const float* db      = (const float*)d_in[8];
    float* out           = (float*)d_out;

    const int B = in_sizes[2] / H_DIM;      // 32768
    dim3 grid((unsigned)(B / 16));          // one 1-wave block per 16 batch rows
    dim3 block(64);
    hipLaunchKernelGGL(gru_mfma11, grid, block, 0, stream,
                       feat, init_in, init_h, Wk, Rk, bx, bh, dw, db, out);
}